// Round 12
// baseline (2190.695 us; speedup 1.0000x reference)
//
#include <hip/hip_runtime.h>

#define GRID    256
#define BLOCK   512
#define NWAVES  (BLOCK / 64)
#define CHUNK   7813    // ceil(2e6/256) verts per block

typedef unsigned long long u64;

// ---------------- fence-free tagged publish (cross-XCD safe) ----------------
// Relaxed agent-scope atomics on gfx950 = global_load/store ... sc0 sc1:
// bypass caches, hit the coherence point, no maintenance ops.
// Per-step protocol history: grid.sync 28.5us (r2); acquire polls 33us (r3);
// release-fence 12.7us (r4); fence-free tagged words 9.7us (r5); SoA
// all-to-all 8.4us (r6); leader+broadcast+barrier-handoff 6.05us (r8).
// Verified-bad variants: all-wave receive (r9, poll storm), LDS-flag spins
// (r10, slower than s_barrier), contiguous-segment float4 scan (r11,
// 6.65e7 LDS bank conflicts: lane stride 64B -> 2 bank groups).
// r12 = r8 + hoisted inertia inversion + broadcast-first (both verified),
// scan restored to r8's conflict-free scalar stride-BLOCK pattern.
__device__ __forceinline__ u64 rec_load(const u64* p) {
  return __hip_atomic_load(p, __ATOMIC_RELAXED, __HIP_MEMORY_SCOPE_AGENT);
}
__device__ __forceinline__ void rec_store(u64* p, u64 v) {
  __hip_atomic_store(p, v, __ATOMIC_RELAXED, __HIP_MEMORY_SCOPE_AGENT);
}
__device__ __forceinline__ u64 rec_pack(float f, unsigned tag) {
  return (u64)__float_as_uint(f) | ((u64)tag << 32);
}

// ---------------- block reduction helper (one-time phases only) ----------------
template <int NV>
__device__ __forceinline__ void block_reduce(float* v, float* sm) {
  #pragma unroll
  for (int off = 32; off > 0; off >>= 1) {
    #pragma unroll
    for (int k = 0; k < NV; ++k) v[k] += __shfl_down(v[k], off, 64);
  }
  const int lane = threadIdx.x & 63;
  const int wid  = threadIdx.x >> 6;
  if (lane == 0) {
    #pragma unroll
    for (int k = 0; k < NV; ++k) sm[wid * NV + k] = v[k];
  }
  __syncthreads();
  if (threadIdx.x == 0) {
    #pragma unroll
    for (int w = 1; w < NWAVES; ++w) {
      #pragma unroll
      for (int k = 0; k < NV; ++k) v[k] += sm[w * NV + k];
    }
  }
  __syncthreads();
}

// ---------------- 3x3 helpers (row-major float[9]) ----------------
__device__ __forceinline__ void mat3_mul(const float* A, const float* B, float* C) {
  #pragma unroll
  for (int i = 0; i < 3; ++i)
    #pragma unroll
    for (int j = 0; j < 3; ++j)
      C[i*3+j] = A[i*3+0]*B[0*3+j] + A[i*3+1]*B[1*3+j] + A[i*3+2]*B[2*3+j];
}
__device__ __forceinline__ void mat3_mul_bt(const float* A, const float* B, float* C) {
  #pragma unroll
  for (int i = 0; i < 3; ++i)
    #pragma unroll
    for (int j = 0; j < 3; ++j)
      C[i*3+j] = A[i*3+0]*B[j*3+0] + A[i*3+1]*B[j*3+1] + A[i*3+2]*B[j*3+2];
}
__device__ __forceinline__ void mat3_inv(const float* m, float* inv) {
  float A =  (m[4]*m[8] - m[5]*m[7]);
  float B = -(m[3]*m[8] - m[5]*m[6]);
  float C =  (m[3]*m[7] - m[4]*m[6]);
  float det = m[0]*A + m[1]*B + m[2]*C;
  float id = 1.0f / det;
  inv[0] = A * id;
  inv[1] = -(m[1]*m[8] - m[2]*m[7]) * id;
  inv[2] =  (m[1]*m[5] - m[2]*m[4]) * id;
  inv[3] = B * id;
  inv[4] =  (m[0]*m[8] - m[2]*m[6]) * id;
  inv[5] = -(m[0]*m[5] - m[2]*m[3]) * id;
  inv[6] = C * id;
  inv[7] = -(m[0]*m[7] - m[1]*m[6]) * id;
  inv[8] =  (m[0]*m[4] - m[1]*m[3]) * id;
}

__global__ __launch_bounds__(BLOCK)
void sim_kernel(const float* __restrict__ xg,
                const float* __restrict__ mc_p,
                const float* __restrict__ itr_p,
                const float* __restrict__ iq_p,
                const float* __restrict__ iv_p,
                const float* __restrict__ kn_p,
                const float* __restrict__ mu_p,
                const float* __restrict__ ldp_p,
                const float* __restrict__ adp_p,
                float* __restrict__ out,
                u64* __restrict__ ws,
                int N, int T)
{
  const int tid  = threadIdx.x;
  const int bid  = blockIdx.x;
  const int lane = tid & 63;
  const int wid  = tid >> 6;

  extern __shared__ float dyn[];
  float* sXx = dyn;
  float* sXy = dyn + CHUNK;
  float* sXz = dyn + 2 * CHUNK;
  __shared__ float s_red6[NWAVES * 6];   // one-time phases
  __shared__ float s_red4[NWAVES * 4];   // hot loop: block partial
  __shared__ float s_red2[NWAVES * 2];   // hot loop: leader gather
  __shared__ float s_plane[8];

  // fp32 constants exactly as the fp32 reference sees them
  const float nx  = (float)(-0.3420201433256687);   // -sin(20deg)
  const float ny  = (float)( 0.9396926207859084);   //  cos(20deg)
  const float DTF = (float)(1.0 / 60.0 / 10.0);
  const float HDT = (float)(0.5 * (1.0 / 60.0 / 10.0));
  const float DTH = (float)(-0.9396926207859084 * 0.1); // -COS_S*INIT_HEIGHT
  const float GYDT = -9.8f * (float)(1.0 / 60.0 / 10.0);

  const float mc0 = mc_p[0], mc1 = mc_p[1], mc2 = mc_p[2];

  // workspace (u64), tagged words; poison 0xAAAAAAAA != any tag (1..240, 0xC0FFEE)
  u64* part0 = ws;            // 4*GRID comp-major: word c*GRID+b (even steps)
  u64* part1 = ws + 1024;     // odd steps
  u64* st    = ws + 2048;     // 2 slots * 8 replicas * 8 words
  u64* bufI  = ws + 2176;     // 6*GRID inertia partials

  const int vstart = bid * CHUNK;
  int cl = N - vstart; if (cl > CHUNK) cl = CHUNK; if (cl < 0) cl = 0;

  // ---- stage this block's slice of x into LDS (SoA) ----
  for (int i = tid; i < cl; i += BLOCK) {
    const float* p = xg + (size_t)(vstart + i) * 3;
    sXx[i] = p[0]; sXy[i] = p[1]; sXz[i] = p[2];
  }
  __syncthreads();

  // ---- inertia partial over this slice (one-time) ----
  {
    float v6[6] = {0,0,0,0,0,0};
    for (int i = tid; i < cl; i += BLOCK) {
      float r0 = sXx[i] - mc0, r1 = sXy[i] - mc1, r2 = sXz[i] - mc2;
      v6[0] += r0*r0; v6[1] += r1*r1; v6[2] += r2*r2;
      v6[3] += r0*r1; v6[4] += r0*r2; v6[5] += r1*r2;
    }
    block_reduce<6>(v6, s_red6);
    if (tid == 0) {
      #pragma unroll
      for (int k = 0; k < 6; ++k) rec_store(bufI + k * GRID + bid, rec_pack(v6[k], 0xC0FFEEu));
    }
  }

  // ---- leader gathers inertia ----
  float In[9];
  if (bid == 0) {
    float v6[6] = {0,0,0,0,0,0};
    if (tid < GRID) {
      u64 r[6];
      int f = 0;
      for (;;) {
        #pragma unroll
        for (int k = 0; k < 6; ++k) r[k] = rec_load(bufI + k * GRID + tid);
        bool ok = true;
        #pragma unroll
        for (int k = 0; k < 6; ++k) ok &= ((unsigned)(r[k] >> 32) == 0xC0FFEEu);
        if (ok) break;
        if ((++f & 15) == 0) __builtin_amdgcn_s_sleep(1);
      }
      #pragma unroll
      for (int k = 0; k < 6; ++k) v6[k] = __uint_as_float((unsigned)r[k]);
    }
    block_reduce<6>(v6, s_red6);
    float trc = v6[0] + v6[1] + v6[2];
    In[0] = trc - v6[0]; In[4] = trc - v6[1]; In[8] = trc - v6[2];
    In[1] = -v6[3]; In[3] = -v6[3];
    In[2] = -v6[4]; In[6] = -v6[4];
    In[5] = -v6[5]; In[7] = -v6[5];
  }

  // ---- initial state; every thread computes identical P_0 ----
  float tr0 = itr_p[0], tr1 = itr_p[1], tr2 = itr_p[2];
  float q0 = iq_p[0], q1 = iq_p[1], q2 = iq_p[2], q3 = iq_p[3];
  {
    float n0 = sqrtf(q0*q0 + q1*q1 + q2*q2 + q3*q3);
    q0 /= n0; q1 /= n0; q2 /= n0; q3 /= n0;
  }
  float v0 = iv_p[0], v1 = iv_p[1], v2 = iv_p[2];
  float om0 = 0.f, om1 = 0.f, om2 = 0.f;
  const float knv = kn_p[0], muv = mu_p[0], ldv = ldp_p[0], adv = adp_p[0];
  const float inv_mass = 1.0f / (float)N;

  float Rm[9];     // leader thread 0 persistent
  float Ii[9];     // hoisted inv(R In R^T), leader thread 0
  float a0, a1, a2, b0, b1, b2, ca, cb;

  {
    // P_0 (all threads; identical fp ops)
    float qn = sqrtf(q0*q0 + q1*q1 + q2*q2 + q3*q3);
    float w = q0/qn, xq = q1/qn, yq = q2/qn, zq = q3/qn;
    float R0 = 1.f - 2.f*yq*yq - 2.f*zq*zq, R1 = 2.f*xq*yq - 2.f*w*zq, R2 = 2.f*xq*zq + 2.f*w*yq;
    float R3 = 2.f*xq*yq + 2.f*w*zq, R4 = 1.f - 2.f*xq*xq - 2.f*zq*zq, R5 = 2.f*yq*zq - 2.f*w*xq;
    float R6 = 2.f*xq*zq - 2.f*w*yq, R7 = 2.f*yq*zq + 2.f*w*xq, R8 = 1.f - 2.f*xq*xq - 2.f*yq*yq;
    a0 = R0*nx + R3*ny; a1 = R1*nx + R4*ny; a2 = R2*nx + R5*ny;
    float w0 = ny*om2, w1 = -nx*om2, w2 = nx*om1 - ny*om0;   // = 0 exactly
    b0 = R0*w0 + R3*w1 + R6*w2;
    b1 = R1*w0 + R4*w1 + R7*w2;
    b2 = R2*w0 + R5*w1 + R8*w2;
    ca = DTH - ((tr0 + mc0)*nx + (tr1 + mc1)*ny);
    cb = -(v0*nx + v1*ny);
    if (bid == 0 && tid == 0) {
      Rm[0]=R0; Rm[1]=R1; Rm[2]=R2; Rm[3]=R3; Rm[4]=R4; Rm[5]=R5; Rm[6]=R6; Rm[7]=R7; Rm[8]=R8;
      s_plane[0]=a0; s_plane[1]=a1; s_plane[2]=a2;
      s_plane[3]=b0; s_plane[4]=b1; s_plane[5]=b2;
      s_plane[6]=ca; s_plane[7]=cb;
      float Tm[9]; mat3_mul(Rm, In, Tm);
      float Iw[9]; mat3_mul_bt(Tm, Rm, Iw);
      mat3_inv(Iw, Ii);
    }
  }

  if (bid == 0) {
    // =================== LEADER BLOCK ===================
    for (int t = 0; t < T; ++t) {
      __syncthreads();   // s_plane handoff from end of previous step / init
      a0 = s_plane[0]; a1 = s_plane[1]; a2 = s_plane[2];
      b0 = s_plane[3]; b1 = s_plane[4]; b2 = s_plane[5];
      ca = s_plane[6]; cb = s_plane[7];

      float acc[4] = {0.f, 0.f, 0.f, 0.f};
      for (int i = tid; i < cl; i += BLOCK) {
        float x0 = sXx[i], x1 = sXy[i], x2 = sXz[i];
        float da = x0*a0 + x1*a1 + x2*a2;
        float db = x0*b0 + x1*b1 + x2*b2;
        if (da < ca && db < cb) { acc[0] += 1.f; acc[1] += x0; acc[2] += x1; acc[3] += x2; }
      }
      #pragma unroll
      for (int off = 32; off > 0; off >>= 1) {
        #pragma unroll
        for (int k = 0; k < 4; ++k) acc[k] += __shfl_down(acc[k], off, 64);
      }
      if (lane == 0) {
        #pragma unroll
        for (int k = 0; k < 4; ++k) s_red4[wid * 4 + k] = acc[k];
      }
      __syncthreads();
      const unsigned want = (unsigned)(t + 1);
      u64* pb = (t & 1) ? part1 : part0;
      if (tid == 0) {
        #pragma unroll
        for (int w = 1; w < NWAVES; ++w) {
          #pragma unroll
          for (int k = 0; k < 4; ++k) acc[k] += s_red4[w * 4 + k];
        }
        #pragma unroll
        for (int k = 0; k < 4; ++k) rec_store(pb + k * GRID + 0, rec_pack(acc[k], want));
      }

      // per-thread spin: words tid (comps 0/1) and tid+512 (comps 2/3)
      u64 wA, wB;
      {
        int f = 0;
        for (;;) {
          wA = rec_load(pb + tid);
          wB = rec_load(pb + 512 + tid);
          if ((unsigned)(wA >> 32) == want && (unsigned)(wB >> 32) == want) break;
          if ((++f & 15) == 0) __builtin_amdgcn_s_sleep(1);
        }
      }
      float pA = __uint_as_float((unsigned)wA);
      float pB = __uint_as_float((unsigned)wB);
      #pragma unroll
      for (int off = 32; off > 0; off >>= 1) {
        pA += __shfl_down(pA, off, 64);
        pB += __shfl_down(pB, off, 64);
      }
      if (lane == 0) { s_red2[wid * 2] = pA; s_red2[wid * 2 + 1] = pB; }
      __syncthreads();

      if (tid == 0) {
        // waves 0-3: comps 0(A)/2(B); waves 4-7: comps 1/3
        float tot0 = s_red2[0] + s_red2[2]  + s_red2[4]  + s_red2[6];
        float tot2 = s_red2[1] + s_red2[3]  + s_red2[5]  + s_red2[7];
        float tot1 = s_red2[8] + s_red2[10] + s_red2[12] + s_red2[14];
        float tot3 = s_red2[9] + s_red2[11] + s_red2[13] + s_red2[15];

        float num = tot0;
        float numf = fmaxf(num, 1.0f);
        float ri0 = tot1 / numf, ri1 = tot2 / numf, ri2 = tot3 / numf;
        float Ri0 = Rm[0]*ri0 + Rm[1]*ri1 + Rm[2]*ri2;
        float Ri1 = Rm[3]*ri0 + Rm[4]*ri1 + Rm[5]*ri2;
        float Ri2 = Rm[6]*ri0 + Rm[7]*ri1 + Rm[8]*ri2;
        float dv0 = 0.f, dv1 = 0.f, dv2 = 0.f, dm0 = 0.f, dm1 = 0.f, dm2 = 0.f;
        if (num > 0.0f) {
          float vi0 = v0 + om1*Ri2 - om2*Ri1;
          float vi1 = v1 + om2*Ri0 - om0*Ri2;
          float vi2 = v2 + om0*Ri1 - om1*Ri0;
          float vdn = vi0*nx + vi1*ny;
          float vn0 = vdn*nx, vn1 = vdn*ny;           // vn2 == 0 exactly
          float vt0 = vi0 - vn0, vt1 = vi1 - vn1, vt2 = vi2;
          float nvn = sqrtf(vn0*vn0 + vn1*vn1);
          float nvt = sqrtf(vt0*vt0 + vt1*vt1 + vt2*vt2);
          float alpha = fmaxf(1.0f - muv*(1.0f + knv)*(nvn/(nvt + 1e-6f)), 0.0f);
          float dvi0 = (-knv*vn0 + alpha*vt0) - vi0;
          float dvi1 = (-knv*vn1 + alpha*vt1) - vi1;
          float dvi2 = (alpha*vt2) - vi2;
          // Ii hoisted (computed after previous broadcast)
          float Cx[9] = {0.f, -Ri2, Ri1,  Ri2, 0.f, -Ri0,  -Ri1, Ri0, 0.f};
          float T2[9]; mat3_mul(Cx, Ii, T2);
          float T3[9]; mat3_mul(T2, Cx, T3);
          float K[9];
          #pragma unroll
          for (int k = 0; k < 9; ++k) K[k] = -T3[k];
          K[0] += inv_mass; K[4] += inv_mass; K[8] += inv_mass;
          float Ki[9]; mat3_inv(K, Ki);
          float J0 = Ki[0]*dvi0 + Ki[1]*dvi1 + Ki[2]*dvi2;
          float J1 = Ki[3]*dvi0 + Ki[4]*dvi1 + Ki[5]*dvi2;
          float J2 = Ki[6]*dvi0 + Ki[7]*dvi1 + Ki[8]*dvi2;
          dv0 = J0*inv_mass; dv1 = J1*inv_mass; dv2 = J2*inv_mass;
          float c0 = -Ri2*J1 + Ri1*J2;
          float c1 =  Ri2*J0 - Ri0*J2;
          float c2 = -Ri1*J0 + Ri0*J1;
          dm0 = Ii[0]*c0 + Ii[1]*c1 + Ii[2]*c2;
          dm1 = Ii[3]*c0 + Ii[4]*c1 + Ii[5]*c2;
          dm2 = Ii[6]*c0 + Ii[7]*c1 + Ii[8]*c2;
        }
        v0 = v0*ldv + dv0;
        v1 = (v1 + GYDT)*ldv + dv1;
        v2 = v2*ldv + dv2;
        om0 = om0*adv + dm0; om1 = om1*adv + dm1; om2 = om2*adv + dm2;
        tr0 = tr0 + DTF*v0; tr1 = tr1 + DTF*v1; tr2 = tr2 + DTF*v2;
        float wx = om0*HDT, wy = om1*HDT, wz = om2*HDT;
        float dq0 = -wx*q1 - wy*q2 - wz*q3;
        float dq1 =  wx*q0 + wy*q3 - wz*q2;
        float dq2 =  wy*q0 + wz*q1 - wx*q3;
        float dq3 =  wz*q0 + wx*q2 - wy*q1;
        q0 += dq0; q1 += dq1; q2 += dq2; q3 += dq3;
        float qn2 = sqrtf(q0*q0 + q1*q1 + q2*q2 + q3*q3);
        q0 /= qn2; q1 /= qn2; q2 /= qn2; q3 /= qn2;

        // next plane params
        float qn = sqrtf(q0*q0 + q1*q1 + q2*q2 + q3*q3);
        float w = q0/qn, xq = q1/qn, yq = q2/qn, zq = q3/qn;
        Rm[0] = 1.f - 2.f*yq*yq - 2.f*zq*zq; Rm[1] = 2.f*xq*yq - 2.f*w*zq; Rm[2] = 2.f*xq*zq + 2.f*w*yq;
        Rm[3] = 2.f*xq*yq + 2.f*w*zq; Rm[4] = 1.f - 2.f*xq*xq - 2.f*zq*zq; Rm[5] = 2.f*yq*zq - 2.f*w*xq;
        Rm[6] = 2.f*xq*zq - 2.f*w*yq; Rm[7] = 2.f*yq*zq + 2.f*w*xq; Rm[8] = 1.f - 2.f*xq*xq - 2.f*yq*yq;
        float pl[8];
        pl[0] = Rm[0]*nx + Rm[3]*ny;
        pl[1] = Rm[1]*nx + Rm[4]*ny;
        pl[2] = Rm[2]*nx + Rm[5]*ny;
        float w0 = ny*om2, w1 = -nx*om2, w2 = nx*om1 - ny*om0;
        pl[3] = Rm[0]*w0 + Rm[3]*w1 + Rm[6]*w2;
        pl[4] = Rm[1]*w0 + Rm[4]*w1 + Rm[7]*w2;
        pl[5] = Rm[2]*w0 + Rm[5]*w1 + Rm[8]*w2;
        pl[6] = DTH - ((tr0 + mc0)*nx + (tr1 + mc1)*ny);
        pl[7] = -(v0*nx + v1*ny);

        // broadcast FIRST (critical path): 8 replicas x 8 words
        u64* sl = st + (size_t)((t + 1) & 1) * 64;
        #pragma unroll
        for (int r = 0; r < 8; ++r) {
          #pragma unroll
          for (int k = 0; k < 8; ++k) rec_store(sl + r * 8 + k, rec_pack(pl[k], want));
        }
        // off critical path: own-block handoff, output, hoist next Ii
        #pragma unroll
        for (int k = 0; k < 8; ++k) s_plane[k] = pl[k];
        float* o = out + (size_t)t * 7;
        o[0] = tr0; o[1] = tr1; o[2] = tr2;
        o[3] = q0;  o[4] = q1;  o[5] = q2;  o[6] = q3;
        float Tm[9]; mat3_mul(Rm, In, Tm);
        float Iw[9]; mat3_mul_bt(Tm, Rm, Iw);
        mat3_inv(Iw, Ii);
      }
    }
  } else {
    // =================== NON-LEADER BLOCKS ===================
    const int rep = bid & 7;
    for (int t = 0; t < T; ++t) {
      if (t > 0) {
        if (tid < 8) {
          const u64* sl = st + (size_t)(t & 1) * 64 + (size_t)rep * 8;
          u64 r; int f = 0;
          for (;;) {
            r = rec_load(sl + tid);
            if ((unsigned)(r >> 32) == (unsigned)t) break;
            if ((++f & 31) == 0) __builtin_amdgcn_s_sleep(1);
          }
          s_plane[tid] = __uint_as_float((unsigned)r);
        }
        __syncthreads();
        a0 = s_plane[0]; a1 = s_plane[1]; a2 = s_plane[2];
        b0 = s_plane[3]; b1 = s_plane[4]; b2 = s_plane[5];
        ca = s_plane[6]; cb = s_plane[7];
      }

      float acc[4] = {0.f, 0.f, 0.f, 0.f};
      for (int i = tid; i < cl; i += BLOCK) {
        float x0 = sXx[i], x1 = sXy[i], x2 = sXz[i];
        float da = x0*a0 + x1*a1 + x2*a2;
        float db = x0*b0 + x1*b1 + x2*b2;
        if (da < ca && db < cb) { acc[0] += 1.f; acc[1] += x0; acc[2] += x1; acc[3] += x2; }
      }
      #pragma unroll
      for (int off = 32; off > 0; off >>= 1) {
        #pragma unroll
        for (int k = 0; k < 4; ++k) acc[k] += __shfl_down(acc[k], off, 64);
      }
      if (lane == 0) {
        #pragma unroll
        for (int k = 0; k < 4; ++k) s_red4[wid * 4 + k] = acc[k];
      }
      __syncthreads();
      if (tid == 0) {
        #pragma unroll
        for (int w = 1; w < NWAVES; ++w) {
          #pragma unroll
          for (int k = 0; k < 4; ++k) acc[k] += s_red4[w * 4 + k];
        }
        const unsigned want = (unsigned)(t + 1);
        u64* pb = (t & 1) ? part1 : part0;
        #pragma unroll
        for (int k = 0; k < 4; ++k) rec_store(pb + k * GRID + bid, rec_pack(acc[k], want));
      }
      // WAR safety: a block reaches step t+1's writes only after plane t+1
      // arrived, which the leader sends only after consuming this block's
      // step-t partial.
    }
  }
}

extern "C" void kernel_launch(void* const* d_in, const int* in_sizes, int n_in,
                              void* d_out, int out_size, void* d_ws, size_t ws_size,
                              hipStream_t stream) {
  const float* x   = (const float*)d_in[0];
  const float* mc  = (const float*)d_in[1];
  const float* itr = (const float*)d_in[2];
  const float* iq  = (const float*)d_in[3];
  const float* iv  = (const float*)d_in[4];
  const float* kn  = (const float*)d_in[5];
  const float* mu  = (const float*)d_in[6];
  const float* ldp = (const float*)d_in[7];
  const float* adp = (const float*)d_in[8];
  float* out = (float*)d_out;
  u64* ws  = (u64*)d_ws;
  int N = in_sizes[0] / 3;
  int T = out_size / 7;

  const int dyn_lds = 3 * CHUNK * 4;   // 93756 B < 160 KB/CU
  hipFuncSetAttribute((const void*)sim_kernel,
                      hipFuncAttributeMaxDynamicSharedMemorySize, dyn_lds);

  void* args[] = {(void*)&x, (void*)&mc, (void*)&itr, (void*)&iq, (void*)&iv,
                  (void*)&kn, (void*)&mu, (void*)&ldp, (void*)&adp,
                  (void*)&out, (void*)&ws, (void*)&N, (void*)&T};
  // cooperative launch kept ONLY for the co-residency guarantee (no grid.sync inside)
  hipLaunchCooperativeKernel((void*)sim_kernel, dim3(GRID), dim3(BLOCK),
                             args, dyn_lds, stream);
}

// Round 13
// 1453.308 us; speedup vs baseline: 1.5074x; 1.5074x over previous
//
#include <hip/hip_runtime.h>

#define GRID    256
#define BLOCK   512
#define NWAVES  (BLOCK / 64)
#define CHUNK   7813   // ceil(2e6/256); 3*CHUNK*4 = 93756 B dynamic LDS (160 KB/CU)

typedef unsigned long long u64;

// ---------------- fence-free tagged publish (cross-XCD safe) ----------------
// Relaxed agent-scope atomics on gfx950 = global_load/store ... sc0 sc1:
// bypass caches, hit the coherence point, no maintenance ops.
// Per-step protocol history: grid.sync 28.5us (r2); acquire polls 33us (r3);
// release-fence 12.7us (r4); fence-free tagged words 9.7us (r5); SoA
// all-to-all 8.4us (r6); leader + 64-lane-parallel broadcast 6.05us (r8,
// bench 1583us = session minimum). Verified-bad: all-wave receive (r9),
// LDS-flag spins (r10), 64B-stride float4 scan (r11, 6.7e7 bank conflicts),
// single-lane serial broadcast + restructured gather (r12).
// r13 = r8 byte-identical + ONE delta: inv(R*In*R^T) hoisted off the
// critical path (recomputed after the broadcast; numerically identical).
__device__ __forceinline__ u64 rec_load(const u64* p) {
  return __hip_atomic_load(p, __ATOMIC_RELAXED, __HIP_MEMORY_SCOPE_AGENT);
}
__device__ __forceinline__ void rec_store(u64* p, u64 v) {
  __hip_atomic_store(p, v, __ATOMIC_RELAXED, __HIP_MEMORY_SCOPE_AGENT);
}
__device__ __forceinline__ u64 rec_pack(float f, unsigned tag) {
  return (u64)__float_as_uint(f) | ((u64)tag << 32);
}

// ---------------- block reduction: NV values, result in thread 0 ----------------
template <int NV>
__device__ __forceinline__ void block_reduce(float* v, float* sm) {
  #pragma unroll
  for (int off = 32; off > 0; off >>= 1) {
    #pragma unroll
    for (int k = 0; k < NV; ++k) v[k] += __shfl_down(v[k], off, 64);
  }
  const int lane = threadIdx.x & 63;
  const int wid  = threadIdx.x >> 6;
  if (lane == 0) {
    #pragma unroll
    for (int k = 0; k < NV; ++k) sm[wid * NV + k] = v[k];
  }
  __syncthreads();
  if (threadIdx.x == 0) {
    #pragma unroll
    for (int w = 1; w < NWAVES; ++w) {
      #pragma unroll
      for (int k = 0; k < NV; ++k) v[k] += sm[w * NV + k];
    }
  }
  __syncthreads();
}

// ---------------- 3x3 helpers (row-major float[9]) ----------------
__device__ __forceinline__ void mat3_mul(const float* A, const float* B, float* C) {
  #pragma unroll
  for (int i = 0; i < 3; ++i)
    #pragma unroll
    for (int j = 0; j < 3; ++j)
      C[i*3+j] = A[i*3+0]*B[0*3+j] + A[i*3+1]*B[1*3+j] + A[i*3+2]*B[2*3+j];
}
__device__ __forceinline__ void mat3_mul_bt(const float* A, const float* B, float* C) {
  #pragma unroll
  for (int i = 0; i < 3; ++i)
    #pragma unroll
    for (int j = 0; j < 3; ++j)
      C[i*3+j] = A[i*3+0]*B[j*3+0] + A[i*3+1]*B[j*3+1] + A[i*3+2]*B[j*3+2];
}
__device__ __forceinline__ void mat3_inv(const float* m, float* inv) {
  float A =  (m[4]*m[8] - m[5]*m[7]);
  float B = -(m[3]*m[8] - m[5]*m[6]);
  float C =  (m[3]*m[7] - m[4]*m[6]);
  float det = m[0]*A + m[1]*B + m[2]*C;
  float id = 1.0f / det;
  inv[0] = A * id;
  inv[1] = -(m[1]*m[8] - m[2]*m[7]) * id;
  inv[2] =  (m[1]*m[5] - m[2]*m[4]) * id;
  inv[3] = B * id;
  inv[4] =  (m[0]*m[8] - m[2]*m[6]) * id;
  inv[5] = -(m[0]*m[5] - m[2]*m[3]) * id;
  inv[6] = C * id;
  inv[7] = -(m[0]*m[7] - m[1]*m[6]) * id;
  inv[8] =  (m[0]*m[4] - m[1]*m[3]) * id;
}

__global__ __launch_bounds__(BLOCK)
void sim_kernel(const float* __restrict__ xg,
                const float* __restrict__ mc_p,
                const float* __restrict__ itr_p,
                const float* __restrict__ iq_p,
                const float* __restrict__ iv_p,
                const float* __restrict__ kn_p,
                const float* __restrict__ mu_p,
                const float* __restrict__ ldp_p,
                const float* __restrict__ adp_p,
                float* __restrict__ out,
                u64* __restrict__ ws,
                int N, int T)
{
  const int tid = threadIdx.x;
  const int bid = blockIdx.x;

  extern __shared__ float dyn[];
  float* sXx = dyn;
  float* sXy = dyn + CHUNK;
  float* sXz = dyn + 2 * CHUNK;
  __shared__ float s_red[NWAVES * 8];
  __shared__ float s_plane[8];

  // fp32 constants exactly as the fp32 reference sees them
  const float nx  = (float)(-0.3420201433256687);   // -sin(20deg)
  const float ny  = (float)( 0.9396926207859084);   //  cos(20deg)
  const float DTF = (float)(1.0 / 60.0 / 10.0);
  const float HDT = (float)(0.5 * (1.0 / 60.0 / 10.0));
  const float DTH = (float)(-0.9396926207859084 * 0.1); // -COS_S*INIT_HEIGHT
  const float GYDT = -9.8f * (float)(1.0 / 60.0 / 10.0);

  const float mc0 = mc_p[0], mc1 = mc_p[1], mc2 = mc_p[2];

  // workspace layout (u64), all tagged words; poison 0xAAAAAAAA never equals
  // any tag (1..240, 0xC0FFEE):
  u64* part0 = ws;                    // 4*GRID  partials, even steps (SoA)
  u64* part1 = ws + 4 * GRID;         // 4*GRID  partials, odd steps
  u64* st    = ws + 8 * GRID;         // 2 bufs * 8 replicas * 8 words = 128
  u64* bufI  = ws + 8 * GRID + 128;   // 6*GRID  inertia partials (SoA)

  const int vstart = bid * CHUNK;
  int cl = N - vstart; if (cl > CHUNK) cl = CHUNK; if (cl < 0) cl = 0;

  // ---- stage this block's slice of x into LDS (SoA), single global pass ----
  for (int i = tid; i < cl; i += BLOCK) {
    const float* p = xg + (size_t)(vstart + i) * 3;
    sXx[i] = p[0]; sXy[i] = p[1]; sXz[i] = p[2];
  }
  __syncthreads();

  // ---- inertia partial: S[i][j] = sum r_i r_j over this slice ----
  {
    float v6[6] = {0,0,0,0,0,0};
    for (int i = tid; i < cl; i += BLOCK) {
      float r0 = sXx[i] - mc0, r1 = sXy[i] - mc1, r2 = sXz[i] - mc2;
      v6[0] += r0*r0; v6[1] += r1*r1; v6[2] += r2*r2;
      v6[3] += r0*r1; v6[4] += r0*r2; v6[5] += r1*r2;
    }
    block_reduce<6>(v6, s_red);
    if (tid == 0) {
      #pragma unroll
      for (int k = 0; k < 6; ++k) rec_store(bufI + k * GRID + bid, rec_pack(v6[k], 0xC0FFEEu));
    }
  }

  // ---- ONLY the leader gathers inertia (physics runs only there) ----
  float In[9];
  if (bid == 0) {
    float v6[6] = {0,0,0,0,0,0};
    if (tid < GRID) {
      u64 r[6];
      int f = 0;
      for (;;) {
        #pragma unroll
        for (int k = 0; k < 6; ++k) r[k] = rec_load(bufI + k * GRID + tid);
        bool ok = true;
        #pragma unroll
        for (int k = 0; k < 6; ++k) ok &= ((unsigned)(r[k] >> 32) == 0xC0FFEEu);
        if (ok) break;
        if ((++f & 15) == 0) __builtin_amdgcn_s_sleep(1);
      }
      #pragma unroll
      for (int k = 0; k < 6; ++k) v6[k] = __uint_as_float((unsigned)r[k]);
    }
    block_reduce<6>(v6, s_red);
    float trc = v6[0] + v6[1] + v6[2];
    In[0] = trc - v6[0]; In[4] = trc - v6[1]; In[8] = trc - v6[2];
    In[1] = -v6[3]; In[3] = -v6[3];
    In[2] = -v6[4]; In[6] = -v6[4];
    In[5] = -v6[5]; In[7] = -v6[5];
  }

  // ---- initial state; EVERY block's thread 0 computes identical P_0 ----
  float tr0 = itr_p[0], tr1 = itr_p[1], tr2 = itr_p[2];
  float q0 = iq_p[0], q1 = iq_p[1], q2 = iq_p[2], q3 = iq_p[3];
  {
    float n0 = sqrtf(q0*q0 + q1*q1 + q2*q2 + q3*q3);
    q0 /= n0; q1 /= n0; q2 /= n0; q3 /= n0;
  }
  float v0 = iv_p[0], v1 = iv_p[1], v2 = iv_p[2];
  float om0 = 0.f, om1 = 0.f, om2 = 0.f;
  const float knv = kn_p[0], muv = mu_p[0], ldv = ldp_p[0], adv = adp_p[0];
  const float inv_mass = 1.0f / (float)N;

  float Rm[9];   // persists in leader's thread 0 across steps
  float Ii[9];   // hoisted inv(R In R^T), leader thread 0

  if (tid == 0) {
    float qn = sqrtf(q0*q0 + q1*q1 + q2*q2 + q3*q3);
    float w = q0/qn, xq = q1/qn, yq = q2/qn, zq = q3/qn;
    Rm[0] = 1.f - 2.f*yq*yq - 2.f*zq*zq; Rm[1] = 2.f*xq*yq - 2.f*w*zq; Rm[2] = 2.f*xq*zq + 2.f*w*yq;
    Rm[3] = 2.f*xq*yq + 2.f*w*zq; Rm[4] = 1.f - 2.f*xq*xq - 2.f*zq*zq; Rm[5] = 2.f*yq*zq - 2.f*w*xq;
    Rm[6] = 2.f*xq*zq - 2.f*w*yq; Rm[7] = 2.f*yq*zq + 2.f*w*xq; Rm[8] = 1.f - 2.f*xq*xq - 2.f*yq*yq;
    float a0 = Rm[0]*nx + Rm[3]*ny;
    float a1 = Rm[1]*nx + Rm[4]*ny;
    float a2 = Rm[2]*nx + Rm[5]*ny;
    float w0 = ny*om2, w1 = -nx*om2, w2 = nx*om1 - ny*om0;   // = 0 exactly
    float b0 = Rm[0]*w0 + Rm[3]*w1 + Rm[6]*w2;
    float b1 = Rm[1]*w0 + Rm[4]*w1 + Rm[7]*w2;
    float b2 = Rm[2]*w0 + Rm[5]*w1 + Rm[8]*w2;
    float ca = DTH - ((tr0 + mc0)*nx + (tr1 + mc1)*ny);
    float cb = -(v0*nx + v1*ny);
    s_plane[0] = a0; s_plane[1] = a1; s_plane[2] = a2;
    s_plane[3] = b0; s_plane[4] = b1; s_plane[5] = b2;
    s_plane[6] = ca; s_plane[7] = cb;
    if (bid == 0) {
      // hoisted initial inertia inversion (off the hot loop)
      float Tm[9]; mat3_mul(Rm, In, Tm);
      float Iw[9]; mat3_mul_bt(Tm, Rm, Iw);
      mat3_inv(Iw, Ii);
    }
  }
  __syncthreads();

  for (int t = 0; t < T; ++t) {
    const float a0 = s_plane[0], a1 = s_plane[1], a2 = s_plane[2];
    const float b0 = s_plane[3], b1 = s_plane[4], b2 = s_plane[5];
    const float ca = s_plane[6], cb = s_plane[7];

    // ---- masked reduction over this block's LDS slice ----
    float acc[4] = {0.f, 0.f, 0.f, 0.f};
    for (int i = tid; i < cl; i += BLOCK) {
      float x0 = sXx[i], x1 = sXy[i], x2 = sXz[i];
      float da = x0*a0 + x1*a1 + x2*a2;
      float db = x0*b0 + x1*b1 + x2*b2;
      if (da < ca && db < cb) { acc[0] += 1.f; acc[1] += x0; acc[2] += x1; acc[3] += x2; }
    }
    block_reduce<4>(acc, s_red);

    // ---- publish partial: 4 tagged words (SoA), no fence ----
    const unsigned want = (unsigned)(t + 1);
    u64* pb = (t & 1) ? part1 : part0;   // distance-2 reuse WAR-safe: leader
                                         // consumes partials t before P_{t+1},
                                         // and any block writes t+2 only after
                                         // seeing P_{t+2} (skew <= 1 step).
    if (tid == 0) {
      #pragma unroll
      for (int k = 0; k < 4; ++k) rec_store(pb + k * GRID + bid, rec_pack(acc[k], want));
    }

    if (bid == 0) {
      // ---- leader: gather all 256 partials (coalesced SoA polls) ----
      float tot[4] = {0.f, 0.f, 0.f, 0.f};
      if (tid < GRID) {
        u64 r0, r1, r2, r3;
        int f = 0;
        for (;;) {
          r0 = rec_load(pb + 0 * GRID + tid);
          r1 = rec_load(pb + 1 * GRID + tid);
          r2 = rec_load(pb + 2 * GRID + tid);
          r3 = rec_load(pb + 3 * GRID + tid);
          if ((unsigned)(r0 >> 32) == want && (unsigned)(r1 >> 32) == want &&
              (unsigned)(r2 >> 32) == want && (unsigned)(r3 >> 32) == want) break;
          if ((++f & 15) == 0) __builtin_amdgcn_s_sleep(1);
        }
        tot[0] = __uint_as_float((unsigned)r0);
        tot[1] = __uint_as_float((unsigned)r1);
        tot[2] = __uint_as_float((unsigned)r2);
        tot[3] = __uint_as_float((unsigned)r3);
      }
      block_reduce<4>(tot, s_red);

      // ---- serial physics (leader thread 0 only; Ii pre-hoisted) ----
      if (tid == 0) {
        float num = tot[0];
        float numf = fmaxf(num, 1.0f);
        float ri0 = tot[1] / numf, ri1 = tot[2] / numf, ri2 = tot[3] / numf;
        float Ri0 = Rm[0]*ri0 + Rm[1]*ri1 + Rm[2]*ri2;
        float Ri1 = Rm[3]*ri0 + Rm[4]*ri1 + Rm[5]*ri2;
        float Ri2 = Rm[6]*ri0 + Rm[7]*ri1 + Rm[8]*ri2;
        float dv0 = 0.f, dv1 = 0.f, dv2 = 0.f, dm0 = 0.f, dm1 = 0.f, dm2 = 0.f;
        if (num > 0.0f) {
          float vi0 = v0 + om1*Ri2 - om2*Ri1;
          float vi1 = v1 + om2*Ri0 - om0*Ri2;
          float vi2 = v2 + om0*Ri1 - om1*Ri0;
          float vdn = vi0*nx + vi1*ny;
          float vn0 = vdn*nx, vn1 = vdn*ny;           // vn2 == 0 exactly
          float vt0 = vi0 - vn0, vt1 = vi1 - vn1, vt2 = vi2;
          float nvn = sqrtf(vn0*vn0 + vn1*vn1);
          float nvt = sqrtf(vt0*vt0 + vt1*vt1 + vt2*vt2);
          float alpha = fmaxf(1.0f - muv*(1.0f + knv)*(nvn/(nvt + 1e-6f)), 0.0f);
          float dvi0 = (-knv*vn0 + alpha*vt0) - vi0;
          float dvi1 = (-knv*vn1 + alpha*vt1) - vi1;
          float dvi2 = (alpha*vt2) - vi2;
          float Cx[9] = {0.f, -Ri2, Ri1,  Ri2, 0.f, -Ri0,  -Ri1, Ri0, 0.f};
          float T2[9]; mat3_mul(Cx, Ii, T2);
          float T3[9]; mat3_mul(T2, Cx, T3);
          float K[9];
          #pragma unroll
          for (int k = 0; k < 9; ++k) K[k] = -T3[k];
          K[0] += inv_mass; K[4] += inv_mass; K[8] += inv_mass;
          float Ki[9]; mat3_inv(K, Ki);
          float J0 = Ki[0]*dvi0 + Ki[1]*dvi1 + Ki[2]*dvi2;
          float J1 = Ki[3]*dvi0 + Ki[4]*dvi1 + Ki[5]*dvi2;
          float J2 = Ki[6]*dvi0 + Ki[7]*dvi1 + Ki[8]*dvi2;
          dv0 = J0*inv_mass; dv1 = J1*inv_mass; dv2 = J2*inv_mass;
          float c0 = -Ri2*J1 + Ri1*J2;
          float c1 =  Ri2*J0 - Ri0*J2;
          float c2 = -Ri1*J0 + Ri0*J1;
          dm0 = Ii[0]*c0 + Ii[1]*c1 + Ii[2]*c2;
          dm1 = Ii[3]*c0 + Ii[4]*c1 + Ii[5]*c2;
          dm2 = Ii[6]*c0 + Ii[7]*c1 + Ii[8]*c2;
        }
        v0 = v0*ldv + dv0;
        v1 = (v1 + GYDT)*ldv + dv1;
        v2 = v2*ldv + dv2;
        om0 = om0*adv + dm0; om1 = om1*adv + dm1; om2 = om2*adv + dm2;
        tr0 = tr0 + DTF*v0; tr1 = tr1 + DTF*v1; tr2 = tr2 + DTF*v2;
        float wx = om0*HDT, wy = om1*HDT, wz = om2*HDT;
        float dq0 = -wx*q1 - wy*q2 - wz*q3;
        float dq1 =  wx*q0 + wy*q3 - wz*q2;
        float dq2 =  wy*q0 + wz*q1 - wx*q3;
        float dq3 =  wz*q0 + wx*q2 - wy*q1;
        q0 += dq0; q1 += dq1; q2 += dq2; q3 += dq3;
        float qn2 = sqrtf(q0*q0 + q1*q1 + q2*q2 + q3*q3);
        q0 /= qn2; q1 /= qn2; q2 /= qn2; q3 /= qn2;
        float* o = out + (size_t)t * 7;
        o[0] = tr0; o[1] = tr1; o[2] = tr2;
        o[3] = q0;  o[4] = q1;  o[5] = q2;  o[6] = q3;
        // next step's plane params
        float qn = sqrtf(q0*q0 + q1*q1 + q2*q2 + q3*q3);
        float w = q0/qn, xq = q1/qn, yq = q2/qn, zq = q3/qn;
        Rm[0] = 1.f - 2.f*yq*yq - 2.f*zq*zq; Rm[1] = 2.f*xq*yq - 2.f*w*zq; Rm[2] = 2.f*xq*zq + 2.f*w*yq;
        Rm[3] = 2.f*xq*yq + 2.f*w*zq; Rm[4] = 1.f - 2.f*xq*xq - 2.f*zq*zq; Rm[5] = 2.f*yq*zq - 2.f*w*xq;
        Rm[6] = 2.f*xq*zq - 2.f*w*yq; Rm[7] = 2.f*yq*zq + 2.f*w*xq; Rm[8] = 1.f - 2.f*xq*xq - 2.f*yq*yq;
        float na0 = Rm[0]*nx + Rm[3]*ny;
        float na1 = Rm[1]*nx + Rm[4]*ny;
        float na2 = Rm[2]*nx + Rm[5]*ny;
        float w0 = ny*om2, w1 = -nx*om2, w2 = nx*om1 - ny*om0;
        float nb0 = Rm[0]*w0 + Rm[3]*w1 + Rm[6]*w2;
        float nb1 = Rm[1]*w0 + Rm[4]*w1 + Rm[7]*w2;
        float nb2 = Rm[2]*w0 + Rm[5]*w1 + Rm[8]*w2;
        float nca = DTH - ((tr0 + mc0)*nx + (tr1 + mc1)*ny);
        float ncb = -(v0*nx + v1*ny);
        s_plane[0] = na0; s_plane[1] = na1; s_plane[2] = na2;
        s_plane[3] = nb0; s_plane[4] = nb1; s_plane[5] = nb2;
        s_plane[6] = nca; s_plane[7] = ncb;
      }
      __syncthreads();
      // ---- broadcast: 8 replicas x 8 words, ONE coalesced 64-lane store ----
      if (tid < 64) {
        u64* sl = st + (size_t)((t + 1) & 1) * 64;
        rec_store(sl + tid, rec_pack(s_plane[tid & 7], want));
      }
      // off critical path: hoist next step's inertia inversion
      if (tid == 0) {
        float Tm[9]; mat3_mul(Rm, In, Tm);
        float Iw[9]; mat3_mul_bt(Tm, Rm, Iw);
        mat3_inv(Iw, Ii);
      }
    } else {
      // ---- non-leader: poll my replica of the state line (1 line) ----
      if (tid < 8) {
        const u64* sl = st + (size_t)((t + 1) & 1) * 64 + (size_t)(bid & 7) * 8;
        u64 r; int f = 0;
        for (;;) {
          r = rec_load(sl + tid);
          if ((unsigned)(r >> 32) == want) break;
          if ((++f & 31) == 0) __builtin_amdgcn_s_sleep(1);
        }
        s_plane[tid] = __uint_as_float((unsigned)r);
      }
      __syncthreads();
    }
  }
}

extern "C" void kernel_launch(void* const* d_in, const int* in_sizes, int n_in,
                              void* d_out, int out_size, void* d_ws, size_t ws_size,
                              hipStream_t stream) {
  const float* x   = (const float*)d_in[0];
  const float* mc  = (const float*)d_in[1];
  const float* itr = (const float*)d_in[2];
  const float* iq  = (const float*)d_in[3];
  const float* iv  = (const float*)d_in[4];
  const float* kn  = (const float*)d_in[5];
  const float* mu  = (const float*)d_in[6];
  const float* ldp = (const float*)d_in[7];
  const float* adp = (const float*)d_in[8];
  float* out = (float*)d_out;
  u64* ws  = (u64*)d_ws;
  int N = in_sizes[0] / 3;
  int T = out_size / 7;

  const int dyn_lds = 3 * CHUNK * 4;   // 93756 B < 160 KB/CU
  hipFuncSetAttribute((const void*)sim_kernel,
                      hipFuncAttributeMaxDynamicSharedMemorySize, dyn_lds);

  void* args[] = {(void*)&x, (void*)&mc, (void*)&itr, (void*)&iq, (void*)&iv,
                  (void*)&kn, (void*)&mu, (void*)&ldp, (void*)&adp,
                  (void*)&out, (void*)&ws, (void*)&N, (void*)&T};
  // cooperative launch kept ONLY for the co-residency guarantee (no grid.sync inside)
  hipLaunchCooperativeKernel((void*)sim_kernel, dim3(GRID), dim3(BLOCK),
                             args, dyn_lds, stream);
}